// Round 7
// baseline (4178.852 us; speedup 1.0000x reference)
//
#include <hip/hip_runtime.h>

typedef unsigned short u16;
typedef unsigned int u32;
typedef unsigned long long ull;
typedef __attribute__((ext_vector_type(8))) short bf16x8;
typedef __attribute__((ext_vector_type(4))) float f32x4;

#define B_   128
#define T_   512
#define NOBS 256
#define H_   512
#define G4   2048
#define NACT 32
#define M_   (B_*T_)   // 65536
#define GR   8         // batch islands
#define ROWS 16        // batch rows per island
#define UN   16        // hidden units per WG
#define ZW   66        // zs row stride (floats), padded: conflict-free
#define TAGB 0x5EED0000u

__device__ __forceinline__ float b2f(u16 s) {
  union { unsigned u; float f; } v; v.u = ((unsigned)s) << 16; return v.f;
}
__device__ __forceinline__ u16 f2b(float f) {
  union { float f; unsigned u; } v; v.f = f;
  unsigned r = v.u + 0x7FFFu + ((v.u >> 16) & 1u);
  return (u16)(r >> 16);
}
__device__ __forceinline__ float sigm(float x) { return 1.f/(1.f+__expf(-x)); }
__device__ __forceinline__ float tanh_f(float x) { return 1.f - 2.f/(1.f+__expf(2.f*x)); }

// global -> LDS direct copy, 16B per lane. ldsbase wave-uniform; HW adds lane*16.
__device__ __forceinline__ void gld16(const void* g, void* ldsbase) {
#if __has_builtin(__builtin_amdgcn_global_load_lds)
  __builtin_amdgcn_global_load_lds((const __attribute__((address_space(1))) void*)g,
                                   (__attribute__((address_space(3))) void*)ldsbase, 16, 0, 0);
#else
  ((float4*)ldsbase)[threadIdx.x & 63] = *(const float4*)g;
#endif
}

// ---------------- prep kernels ----------------
// obs (B,T,NOBS) f32 -> obsT (T,B,NOBS) bf16 ; one 8-elem chunk per thread
__global__ void k_cvt_obsT(const float* __restrict__ in, u16* __restrict__ out) {
  const long i = (long)blockIdx.x*blockDim.x + threadIdx.x;   // chunk id, 8 elems
  const int k8 = (int)(i & (NOBS/8 - 1));
  const long row = i >> 5;                 // t*B + b
  const int t = (int)(row >> 7), b = (int)(row & (B_-1));
  const float* src = in + ((long)b*T_ + t)*NOBS + k8*8;
  ushort2 o[4];
  #pragma unroll
  for (int q = 0; q < 4; ++q) {
    o[q].x = f2b(src[q*2]);
    o[q].y = f2b(src[q*2+1]);
  }
  *(ushort2*)&out[i*8+0] = o[0]; *(ushort2*)&out[i*8+2] = o[1];
  *(ushort2*)&out[i*8+4] = o[2]; *(ushort2*)&out[i*8+6] = o[3];
}

// h0 (B,H) f32 -> tagged granules {h[2p],h[2p+1], tag=TAGB+0} in plane 0
__global__ void k_tagh0(const float* __restrict__ h0, ull* __restrict__ hg) {
  const int i = blockIdx.x*256 + threadIdx.x;   // granule id = b*256 + p
  const int row = i >> 8, p = i & 255;
  unsigned h01 = (unsigned)f2b(h0[row*H_ + 2*p]) |
                 ((unsigned)f2b(h0[row*H_ + 2*p + 1]) << 16);
  hg[i] = (ull)h01 | ((ull)TAGB << 32);
}

// out (C,R) bf16 <- in (R,C) f32 :  out[c*R+r] = in[r*C+c]
__global__ void k_transpose(const float* __restrict__ in, u16* __restrict__ out, int R, int C) {
  int i = blockIdx.x*blockDim.x + threadIdx.x;
  if (i < R*C) {
    int c = i / R, r = i - c*R;
    out[i] = f2b(in[r*C + c]);
  }
}

// ---------------- GEMM: C(M,N) = A(M,K) @ BT(N,K)^T, bf16 in/out, f32 accum ----------------
template<int EPI>
__global__ __launch_bounds__(256) void k_gemm_bt(const u16* __restrict__ A, const u16* __restrict__ BT,
                                                 u16* __restrict__ C, const float* __restrict__ bias,
                                                 int M, int N, int K)
{
  __shared__ u16 As[128*64];
  __shared__ u16 Bs[128*64];
  const int tid = threadIdx.x, wv = tid >> 6, lane = tid & 63;
  const int ntile = N >> 7;
  const int tm = blockIdx.x / ntile, tn = blockIdx.x - tm*ntile;
  const int wr = wv >> 1, wc = wv & 1;
  f32x4 acc[4][4];
  for (int m=0;m<4;++m) for (int n=0;n<4;++n) acc[m][n] = (f32x4){0.f,0.f,0.f,0.f};
  const long abase = (long)tm*128, bbase = (long)tn*128;
  const int kit = K >> 6;
  for (int kt = 0; kt < kit; ++kt) {
    const int k0 = kt << 6;
    #pragma unroll
    for (int q = 0; q < 4; ++q) {
      int off = (wv*4+q)*1024 + lane*16;
      int row = off >> 7, colb = off & 127;
      gld16((const char*)A  + ((abase+row)*K + k0)*2 + colb, (char*)As + (wv*4+q)*1024);
      gld16((const char*)BT + ((bbase+row)*K + k0)*2 + colb, (char*)Bs + (wv*4+q)*1024);
    }
    asm volatile("s_waitcnt vmcnt(0)" ::: "memory");
    __syncthreads();
    const int kg = (lane >> 4) * 8;
    #pragma unroll
    for (int kk = 0; kk < 64; kk += 32) {
      bf16x8 af[4], bfr[4];
      #pragma unroll
      for (int m = 0; m < 4; ++m)
        af[m] = *(const bf16x8*)(As + (wr*64 + m*16 + (lane&15))*64 + kk + kg);
      #pragma unroll
      for (int n = 0; n < 4; ++n)
        bfr[n] = *(const bf16x8*)(Bs + (wc*64 + n*16 + (lane&15))*64 + kk + kg);
      #pragma unroll
      for (int m = 0; m < 4; ++m)
        #pragma unroll
        for (int n = 0; n < 4; ++n)
          acc[m][n] = __builtin_amdgcn_mfma_f32_16x16x32_bf16(af[m], bfr[n], acc[m][n], 0, 0, 0);
    }
    __syncthreads();
  }
  const int rq = (lane >> 4) * 4, cl = lane & 15;
  #pragma unroll
  for (int n = 0; n < 4; ++n) {
    const int coln = (int)bbase + wc*64 + n*16 + cl;
    const float bv = (EPI == 1) ? bias[coln] : 0.f;
    #pragma unroll
    for (int m = 0; m < 4; ++m) {
      const long rowb = abase + wr*64 + m*16 + rq;
      #pragma unroll
      for (int q = 0; q < 4; ++q) {
        float v = acc[m][n][q];
        if (EPI == 1) v = fmaxf(v + bv, 0.f);
        C[(rowb+q)*(long)N + coln] = f2b(v);
      }
    }
  }
}

// ---------------- persistent LSTM scan, v5 ----------------
// grid 256 (1 WG/CU via LDS clamp) = 8 islands x 32 unit-slices. No placement
// assumptions. h exchange through L3 via relaxed AGENT atomics, tag-in-granule
// {2 x bf16, TAGB+t}. 4 rotating planes (read t&3, write (t+1)&3). Publish is
// per-epilogue-thread immediate; consumers validate per MFMA-slice and retry
// only stale slices. One __syncthreads per step (poll subsumes the tail WAR).
__global__ __launch_bounds__(256, 1) void k_scan(
    const u16* __restrict__ obsT, const u16* __restrict__ WxT, const u16* __restrict__ WhT,
    const float* __restrict__ bvec, const float* __restrict__ c0f,
    ull* __restrict__ hg,
    u16* __restrict__ ys, float* __restrict__ outh, float* __restrict__ outc)
{
  __shared__ float zs[2][16*ZW];   // split-K partials
  __shared__ float cst[256];       // cell state slice
  __shared__ float bsl[64];        // bias slice
  __shared__ char pad_[98304];     // occupancy clamp: exactly 1 WG/CU

  const int tid = threadIdx.x, wv = tid >> 6, lane = tid & 63;
  const int wg = blockIdx.x, isl = wg & (GR-1), cg = wg >> 3;
  const int rb0 = isl*ROWS, S0 = cg*UN;
  ((volatile char*)pad_)[tid] = 0;   // keep pad allocated

  const int kh = wv >> 1, ch = wv & 1;     // wave = (k-half, col-half)
  const int C0 = ch*32;
  const int lq = lane >> 4, l15 = lane & 15;
  const int arow = rb0 + l15;

  // ---- load my 24 B-fragments into registers (held for all T steps) ----
  const int j0 = C0 + l15, j1 = j0 + 16;
  const long w0 = (long)((j0 >> 4)*H_ + S0 + (j0 & 15));
  const long w1 = (long)((j1 >> 4)*H_ + S0 + (j1 & 15));
  bf16x8 wbx[4][2], wbh[8][2];
  #pragma unroll
  for (int ks = 0; ks < 4; ++ks) {
    const long k = (long)kh*128 + ks*32 + lq*8;
    wbx[ks][0] = *(const bf16x8*)(WxT + w0*NOBS + k);
    wbx[ks][1] = *(const bf16x8*)(WxT + w1*NOBS + k);
    asm volatile("" : "+v"(wbx[ks][0]), "+v"(wbx[ks][1]));
  }
  #pragma unroll
  for (int ks = 0; ks < 8; ++ks) {
    const long k = (long)kh*256 + ks*32 + lq*8;
    wbh[ks][0] = *(const bf16x8*)(WhT + w0*H_ + k);
    wbh[ks][1] = *(const bf16x8*)(WhT + w1*H_ + k);
    asm volatile("" : "+v"(wbh[ks][0]), "+v"(wbh[ks][1]));
  }

  cst[tid] = c0f[(rb0 + (tid >> 4))*H_ + S0 + (tid & 15)];
  if (tid < 64) bsl[tid] = bvec[(tid >> 4)*H_ + S0 + (tid & 15)];
  __syncthreads();

  // my poll set: granule pos = kh*128 + ks*16 + lq*4 + j  (ks<8, j<4), row arow
  const long pbase = (long)arow*256 + kh*128 + lq*4;

  // obs fragments for t=0 (prefetched one step ahead thereafter)
  bf16x8 ax[4];
  {
    const u16* Ax = obsT + (long)arow*NOBS + kh*128 + lq*8;
    #pragma unroll
    for (int ks = 0; ks < 4; ++ks) ax[ks] = *(const bf16x8*)(Ax + ks*32);
  }

  for (int t = 0; t < T_; ++t) {
    const ull* pc = hg + ((long)(t & 3) << 15);          // read plane (32768 granules)
    ull*       pw = hg + ((long)((t+1) & 3) << 15);      // write plane

    f32x4 acc0 = {0.f,0.f,0.f,0.f}, acc1 = {0.f,0.f,0.f,0.f};

    // phase X: obs_t @ Wx — independent of h, runs before the poll
    #pragma unroll
    for (int ks = 0; ks < 4; ++ks) {
      acc0 = __builtin_amdgcn_mfma_f32_16x16x32_bf16(ax[ks], wbx[ks][0], acc0, 0, 0, 0);
      acc1 = __builtin_amdgcn_mfma_f32_16x16x32_bf16(ax[ks], wbx[ks][1], acc1, 0, 0, 0);
    }

    // poll: per-slice tag validation, retry only stale slices
    ull g[8][4];
    {
      const ull* bp = pc + pbase;
      const unsigned want = TAGB + (unsigned)t;
      #pragma unroll
      for (int ks = 0; ks < 8; ++ks)
        #pragma unroll
        for (int j = 0; j < 4; ++j)
          g[ks][j] = __hip_atomic_load(bp + ks*16 + j, __ATOMIC_RELAXED, __HIP_MEMORY_SCOPE_AGENT);
      unsigned bad = 0xffu;
      int spin = 1 << 22;                      // bailout: fail visibly, never hang
      do {
        unsigned nbad = 0u;
        #pragma unroll
        for (int ks = 0; ks < 8; ++ks) {
          if (bad & (1u << ks)) {
            int ok = ((unsigned)(g[ks][0] >> 32) == want) &
                     ((unsigned)(g[ks][1] >> 32) == want) &
                     ((unsigned)(g[ks][2] >> 32) == want) &
                     ((unsigned)(g[ks][3] >> 32) == want);
            if (!__all(ok)) {
              nbad |= 1u << ks;
              #pragma unroll
              for (int j = 0; j < 4; ++j)
                g[ks][j] = __hip_atomic_load(bp + ks*16 + j, __ATOMIC_RELAXED, __HIP_MEMORY_SCOPE_AGENT);
            }
          }
        }
        bad = nbad;
      } while (bad && --spin);
    }

    // obs prefetch for t+1 (flies under phase H + epilogue)
    bf16x8 axn[4];
    {
      const int tn = (t+1 < T_) ? t+1 : t;
      const u16* Axn = obsT + ((long)tn*B_ + arow)*NOBS + kh*128 + lq*8;
      #pragma unroll
      for (int ks = 0; ks < 4; ++ks) axn[ks] = *(const bf16x8*)(Axn + ks*32);
    }

    // phase H: h @ Wh — fragments straight from polled granules
    #pragma unroll
    for (int ks = 0; ks < 8; ++ks) {
      union { unsigned u[4]; bf16x8 v; } fr;
      #pragma unroll
      for (int j = 0; j < 4; ++j) fr.u[j] = (unsigned)g[ks][j];
      acc0 = __builtin_amdgcn_mfma_f32_16x16x32_bf16(fr.v, wbh[ks][0], acc0, 0, 0, 0);
      acc1 = __builtin_amdgcn_mfma_f32_16x16x32_bf16(fr.v, wbh[ks][1], acc1, 0, 0, 0);
    }
    #pragma unroll
    for (int ks = 0; ks < 4; ++ks) ax[ks] = axn[ks];

    // split-K partials to LDS  (D layout: col=lane&15, row=(lane>>4)*4+q)
    {
      const int zr0 = lq*4, zc = C0 + l15;
      #pragma unroll
      for (int q = 0; q < 4; ++q) {
        zs[kh][(zr0+q)*ZW + zc]      = acc0[q];
        zs[kh][(zr0+q)*ZW + zc + 16] = acc1[q];
      }
    }
    __syncthreads();

    // epilogue: 128 threads, 2 units each; publish tagged granule IMMEDIATELY
    if (tid < 128) {
      const int rr = tid >> 3, pp = tid & 7;
      float hv2[2], cn2[2];
      #pragma unroll
      for (int u = 0; u < 2; ++u) {
        const int sl = 2*pp + u;
        const float* z0 = &zs[0][rr*ZW];
        const float* z1 = &zs[1][rr*ZW];
        const float zi = z0[sl]    + z1[sl]    + bsl[sl];
        const float zf = z0[16+sl] + z1[16+sl] + bsl[16+sl];
        const float zg = z0[32+sl] + z1[32+sl] + bsl[32+sl];
        const float zo = z0[48+sl] + z1[48+sl] + bsl[48+sl];
        const float cv = cst[rr*16 + sl];
        const float cn = sigm(zf)*cv + sigm(zi)*tanh_f(zg);
        hv2[u] = sigm(zo)*tanh_f(cn);
        cn2[u] = cn;
        cst[rr*16 + sl] = cn;
      }
      const unsigned h01 = (unsigned)f2b(hv2[0]) | ((unsigned)f2b(hv2[1]) << 16);
      const int b = rb0 + rr;
      if (t < T_-1)
        __hip_atomic_store(pw + (long)b*256 + cg*8 + pp,
                           (ull)h01 | ((ull)(TAGB + (unsigned)(t+1)) << 32),
                           __ATOMIC_RELAXED, __HIP_MEMORY_SCOPE_AGENT);
      *(unsigned*)(ys + ((long)b*T_ + t)*H_ + S0 + 2*pp) = h01;
      if (t == T_-1) {
        outh[b*H_ + S0 + 2*pp]     = hv2[0];
        outh[b*H_ + S0 + 2*pp + 1] = hv2[1];
        outc[b*H_ + S0 + 2*pp]     = cn2[0];
        outc[b*H_ + S0 + 2*pp + 1] = cn2[1];
      }
    }
    // no trailing barrier: a wave passes poll(t+1) only after its own WG's
    // epilogue published (covers all 128 granules) => zs WAR is ordered.
  }
}

// ---------------- head ----------------
__global__ __launch_bounds__(256) void k_head(const u16* __restrict__ X, const u16* __restrict__ WoT,
    const float* __restrict__ bo, const float* __restrict__ amin, const float* __restrict__ amax,
    float* __restrict__ out)
{
  __shared__ u16 Ws[NACT*H_];
  __shared__ float sc[3*NACT];
  const int tid = threadIdx.x;
  #pragma unroll
  for (int q = 0; q < 8; ++q)
    ((float4*)Ws)[q*256 + tid] = ((const float4*)WoT)[q*256 + tid];
  if (tid < NACT) { sc[tid] = bo[tid]; sc[NACT+tid] = amin[tid]; sc[2*NACT+tid] = amax[tid]; }
  __syncthreads();
  const long r = (long)blockIdx.x*64 + (tid >> 2);
  const int c0 = (tid & 3)*8;
  float acc[8];
  #pragma unroll
  for (int c = 0; c < 8; ++c) acc[c] = 0.f;
  const u16* Arow = X + r*H_;
  for (int kc = 0; kc < H_/8; ++kc) {
    bf16x8 a = *(const bf16x8*)(Arow + kc*8);
    float av[8];
    #pragma unroll
    for (int j = 0; j < 8; ++j) av[j] = b2f((u16)a[j]);
    #pragma unroll
    for (int c = 0; c < 8; ++c) {
      bf16x8 w = *(const bf16x8*)(Ws + (c0+c)*H_ + kc*8);
      #pragma unroll
      for (int j = 0; j < 8; ++j) acc[c] += av[j] * b2f((u16)w[j]);
    }
  }
  #pragma unroll
  for (int c = 0; c < 8; ++c) {
    const int cc = c0 + c;
    const float y = acc[c] + sc[cc];
    const float tv = tanhf(y);
    out[r*NACT + cc] = 0.5f*(tv*(sc[2*NACT+cc]-sc[NACT+cc]) + (sc[2*NACT+cc]+sc[NACT+cc]));
  }
}

extern "C" void kernel_launch(void* const* d_in, const int* in_sizes, int n_in,
                              void* d_out, int out_size, void* d_ws, size_t ws_size,
                              hipStream_t stream) {
  const float* obs = (const float*)d_in[0];
  const float* h0  = (const float*)d_in[1];
  const float* c0  = (const float*)d_in[2];
  const float* Wx  = (const float*)d_in[3];
  const float* Wh  = (const float*)d_in[4];
  const float* bb  = (const float*)d_in[5];
  const float* W1  = (const float*)d_in[6];
  const float* b1  = (const float*)d_in[7];
  const float* W2  = (const float*)d_in[8];
  const float* b2  = (const float*)d_in[9];
  const float* Wo  = (const float*)d_in[10];
  const float* bo  = (const float*)d_in[11];
  const float* amin= (const float*)d_in[12];
  const float* amax= (const float*)d_in[13];

  char* ws = (char*)d_ws;
  // workspace layout (bytes), end ~173.0 MiB:
  u16* obsT  = (u16*)(ws + 0);                 // (T,B,NOBS) bf16, 32 MiB
  u16* ys    = (u16*)(ws + 33554432);          // (B,T,H) bf16, 64 MiB
  u16* t1    = (u16*)(ws + 100663296);         // 64 MiB (dead during scan)
  u16* t2    = (u16*)(ws + 33554432);          // alias ys (dead after W1-GEMM)
  u16* WxT   = (u16*)(ws + 167772160);         // (G4, NOBS)  1 MiB
  u16* WhT   = (u16*)(ws + 168820736);         // (G4, H)     2 MiB
  u16* W1T   = (u16*)(ws + 170917888);         // 0.5 MiB
  u16* W2T   = (u16*)(ws + 171442176);         // 0.5 MiB
  u16* WoT   = (u16*)(ws + 171966464);         // 64 KiB
  ull* hg    = (ull*)(ws + 171999232);         // 4 planes x 256 KiB = 1 MiB

  float* outA = (float*)d_out;
  float* outh = outA + (long)M_*NACT;
  float* outc = outh + B_*H_;

  hipMemsetAsync(hg + 32768, 0, 3*32768*sizeof(ull), stream);  // spare planes tagless
  k_cvt_obsT<<<M_*NOBS/8/256, 256, 0, stream>>>(obs, obsT);
  k_tagh0<<<B_, 256, 0, stream>>>(h0, hg);                     // plane 0 = h0, tag TAGB
  k_transpose<<<2048, 256, 0, stream>>>(Wx, WxT, NOBS, G4);
  k_transpose<<<4096, 256, 0, stream>>>(Wh, WhT, H_, G4);
  k_transpose<<<1024, 256, 0, stream>>>(W1, W1T, H_, H_);
  k_transpose<<<1024, 256, 0, stream>>>(W2, W2T, H_, H_);
  k_transpose<<<64,   256, 0, stream>>>(Wo, WoT, H_, NACT);

  // persistent scan: 256 co-resident WGs (1/CU), tag-validated L3 exchange
  k_scan<<<256, 256, 0, stream>>>(obsT, WxT, WhT, bb, c0, hg, ys, outh, outc);

  // MLP head
  k_gemm_bt<1><<<(M_/128)*(H_/128), 256, 0, stream>>>(ys, W1T, t1, b1, M_, H_, H_);
  k_gemm_bt<1><<<(M_/128)*(H_/128), 256, 0, stream>>>(t1, W2T, t2, b2, M_, H_, H_);
  k_head<<<M_/64, 256, 0, stream>>>(t2, WoT, bo, amin, amax, outA);
}

// Round 8
// 1994.527 us; speedup vs baseline: 2.0952x; 2.0952x over previous
//
#include <hip/hip_runtime.h>

typedef unsigned short u16;
typedef unsigned int u32;
typedef unsigned long long ull;
typedef __attribute__((ext_vector_type(8))) short bf16x8;
typedef __attribute__((ext_vector_type(4))) float f32x4;
typedef __attribute__((ext_vector_type(4))) unsigned u32x4;

#define B_   128
#define T_   512
#define NOBS 256
#define H_   512
#define G4   2048
#define NACT 32
#define M_   (B_*T_)   // 65536
#define GR   8         // batch islands
#define ROWS 16        // batch rows per island
#define UN   16        // hidden units per WG
#define ZW   66        // zs row stride (floats), padded: conflict-free
#define TAGB 0x5EED0000u

__device__ __forceinline__ float b2f(u16 s) {
  union { unsigned u; float f; } v; v.u = ((unsigned)s) << 16; return v.f;
}
__device__ __forceinline__ u16 f2b(float f) {
  union { float f; unsigned u; } v; v.f = f;
  unsigned r = v.u + 0x7FFFu + ((v.u >> 16) & 1u);
  return (u16)(r >> 16);
}
__device__ __forceinline__ float sigm(float x) { return 1.f/(1.f+__expf(-x)); }
__device__ __forceinline__ float tanh_f(float x) { return 1.f - 2.f/(1.f+__expf(2.f*x)); }

// global -> LDS direct copy, 16B per lane. ldsbase wave-uniform; HW adds lane*16.
__device__ __forceinline__ void gld16(const void* g, void* ldsbase) {
#if __has_builtin(__builtin_amdgcn_global_load_lds)
  __builtin_amdgcn_global_load_lds((const __attribute__((address_space(1))) void*)g,
                                   (__attribute__((address_space(3))) void*)ldsbase, 16, 0, 0);
#else
  ((float4*)ldsbase)[threadIdx.x & 63] = *(const float4*)g;
#endif
}

// ---------------- prep kernels ----------------
// obs (B,T,NOBS) f32 -> obsT (T,B,NOBS) bf16 ; one 8-elem chunk per thread
__global__ void k_cvt_obsT(const float* __restrict__ in, u16* __restrict__ out) {
  const long i = (long)blockIdx.x*blockDim.x + threadIdx.x;   // chunk id, 8 elems
  const int k8 = (int)(i & (NOBS/8 - 1));
  const long row = i >> 5;                 // t*B + b
  const int t = (int)(row >> 7), b = (int)(row & (B_-1));
  const float* src = in + ((long)b*T_ + t)*NOBS + k8*8;
  ushort2 o[4];
  #pragma unroll
  for (int q = 0; q < 4; ++q) {
    o[q].x = f2b(src[q*2]);
    o[q].y = f2b(src[q*2+1]);
  }
  *(ushort2*)&out[i*8+0] = o[0]; *(ushort2*)&out[i*8+2] = o[1];
  *(ushort2*)&out[i*8+4] = o[2]; *(ushort2*)&out[i*8+6] = o[3];
}

// h0 (B,H) f32 -> packed bf16 pairs in plane 0 ; flags[0..255] = TAGB
__global__ void k_inith(const float* __restrict__ h0, u16* __restrict__ hp,
                        u32* __restrict__ flags) {
  const int i = blockIdx.x*256 + threadIdx.x;   // pair id = row*256 + p
  const int row = i >> 8, p = i & 255;
  const unsigned h01 = (unsigned)f2b(h0[row*H_ + 2*p]) |
                       ((unsigned)f2b(h0[row*H_ + 2*p + 1]) << 16);
  ((u32*)hp)[row*256 + p] = h01;
  if (i < 256) flags[i] = TAGB;
}

// out (C,R) bf16 <- in (R,C) f32 :  out[c*R+r] = in[r*C+c]
__global__ void k_transpose(const float* __restrict__ in, u16* __restrict__ out, int R, int C) {
  int i = blockIdx.x*blockDim.x + threadIdx.x;
  if (i < R*C) {
    int c = i / R, r = i - c*R;
    out[i] = f2b(in[r*C + c]);
  }
}

// ---------------- GEMM: C(M,N) = A(M,K) @ BT(N,K)^T, bf16 in/out, f32 accum ----------------
template<int EPI>
__global__ __launch_bounds__(256) void k_gemm_bt(const u16* __restrict__ A, const u16* __restrict__ BT,
                                                 u16* __restrict__ C, const float* __restrict__ bias,
                                                 int M, int N, int K)
{
  __shared__ u16 As[128*64];
  __shared__ u16 Bs[128*64];
  const int tid = threadIdx.x, wv = tid >> 6, lane = tid & 63;
  const int ntile = N >> 7;
  const int tm = blockIdx.x / ntile, tn = blockIdx.x - tm*ntile;
  const int wr = wv >> 1, wc = wv & 1;
  f32x4 acc[4][4];
  for (int m=0;m<4;++m) for (int n=0;n<4;++n) acc[m][n] = (f32x4){0.f,0.f,0.f,0.f};
  const long abase = (long)tm*128, bbase = (long)tn*128;
  const int kit = K >> 6;
  for (int kt = 0; kt < kit; ++kt) {
    const int k0 = kt << 6;
    #pragma unroll
    for (int q = 0; q < 4; ++q) {
      int off = (wv*4+q)*1024 + lane*16;
      int row = off >> 7, colb = off & 127;
      gld16((const char*)A  + ((abase+row)*K + k0)*2 + colb, (char*)As + (wv*4+q)*1024);
      gld16((const char*)BT + ((bbase+row)*K + k0)*2 + colb, (char*)Bs + (wv*4+q)*1024);
    }
    asm volatile("s_waitcnt vmcnt(0)" ::: "memory");
    __syncthreads();
    const int kg = (lane >> 4) * 8;
    #pragma unroll
    for (int kk = 0; kk < 64; kk += 32) {
      bf16x8 af[4], bfr[4];
      #pragma unroll
      for (int m = 0; m < 4; ++m)
        af[m] = *(const bf16x8*)(As + (wr*64 + m*16 + (lane&15))*64 + kk + kg);
      #pragma unroll
      for (int n = 0; n < 4; ++n)
        bfr[n] = *(const bf16x8*)(Bs + (wc*64 + n*16 + (lane&15))*64 + kk + kg);
      #pragma unroll
      for (int m = 0; m < 4; ++m)
        #pragma unroll
        for (int n = 0; n < 4; ++n)
          acc[m][n] = __builtin_amdgcn_mfma_f32_16x16x32_bf16(af[m], bfr[n], acc[m][n], 0, 0, 0);
    }
    __syncthreads();
  }
  const int rq = (lane >> 4) * 4, cl = lane & 15;
  #pragma unroll
  for (int n = 0; n < 4; ++n) {
    const int coln = (int)bbase + wc*64 + n*16 + cl;
    const float bv = (EPI == 1) ? bias[coln] : 0.f;
    #pragma unroll
    for (int m = 0; m < 4; ++m) {
      const long rowb = abase + wr*64 + m*16 + rq;
      #pragma unroll
      for (int q = 0; q < 4; ++q) {
        float v = acc[m][n][q];
        if (EPI == 1) v = fmaxf(v + bv, 0.f);
        C[(rowb+q)*(long)N + coln] = f2b(v);
      }
    }
  }
}

// ---------------- persistent LSTM scan, v6: flag release + single-RTT data ----------------
// grid 256 (1 WG/CU via LDS clamp) = 8 islands x 32 unit-slices. Producer: data
// granule stores -> vmcnt(0) -> barrier -> tid0 flag store (release pattern).
// Consumer: each wave polls 1 flag/lane (1KB/WG/round), passes on all >= tag
// (monotone), then loads clean 16B fragments (sc0 sc1) in ONE round trip.
// 4 rotating data planes; producer lead provably <= 1 step -> WAR-free.
__global__ __launch_bounds__(256, 1) void k_scan(
    const u16* __restrict__ obsT, const u16* __restrict__ WxT, const u16* __restrict__ WhT,
    const float* __restrict__ bvec, const float* __restrict__ c0f,
    u16* __restrict__ hp, u32* __restrict__ flags,
    u16* __restrict__ ys, float* __restrict__ outh, float* __restrict__ outc)
{
  __shared__ float zs[2][16*ZW];   // split-K partials
  __shared__ float cst[256];       // cell state slice
  __shared__ float bsl[64];        // bias slice
  __shared__ char pad_[98304];     // occupancy clamp: exactly 1 WG/CU

  const int tid = threadIdx.x, wv = tid >> 6, lane = tid & 63;
  const int wg = blockIdx.x, isl = wg & (GR-1), cg = wg >> 3;
  const int rb0 = isl*ROWS, S0 = cg*UN;
  ((volatile char*)pad_)[tid] = 0;   // keep pad allocated

  const int kh = wv >> 1, ch = wv & 1;     // wave = (k-half, col-half)
  const int C0 = ch*32;
  const int lq = lane >> 4, l15 = lane & 15;
  const int arow = rb0 + l15;

  // ---- load my 24 B-fragments (held in VGPRs; re-pinned every iteration) ----
  const int j0 = C0 + l15, j1 = j0 + 16;
  const long w0 = (long)((j0 >> 4)*H_ + S0 + (j0 & 15));
  const long w1 = (long)((j1 >> 4)*H_ + S0 + (j1 & 15));
  bf16x8 wbx[4][2], wbh[8][2];
  #pragma unroll
  for (int ks = 0; ks < 4; ++ks) {
    const long k = (long)kh*128 + ks*32 + lq*8;
    wbx[ks][0] = *(const bf16x8*)(WxT + w0*NOBS + k);
    wbx[ks][1] = *(const bf16x8*)(WxT + w1*NOBS + k);
  }
  #pragma unroll
  for (int ks = 0; ks < 8; ++ks) {
    const long k = (long)kh*256 + ks*32 + lq*8;
    wbh[ks][0] = *(const bf16x8*)(WhT + w0*H_ + k);
    wbh[ks][1] = *(const bf16x8*)(WhT + w1*H_ + k);
  }

  cst[tid] = c0f[(rb0 + (tid >> 4))*H_ + S0 + (tid & 15)];
  if (tid < 64) bsl[tid] = bvec[(tid >> 4)*H_ + S0 + (tid & 15)];
  __syncthreads();

  // consumer fragment offset within a plane (u16 units)
  const long fofs = (long)arow*H_ + kh*256 + lq*8;
  u32* myflag = flags + isl*32 + cg;
  const u32* pollp = flags + isl*32 + (lane & 31);

  // obs fragments for t=0 (prefetched one step ahead thereafter)
  bf16x8 ax[4];
  {
    const u16* Ax = obsT + (long)arow*NOBS + kh*128 + lq*8;
    #pragma unroll
    for (int ks = 0; ks < 4; ++ks) ax[ks] = *(const bf16x8*)(Ax + ks*32);
  }

  for (int t = 0; t < T_; ++t) {
    // force weight residency at loop top (defeats per-step reload)
    asm volatile("" : "+v"(wbx[0][0]), "+v"(wbx[0][1]), "+v"(wbx[1][0]), "+v"(wbx[1][1]),
                      "+v"(wbx[2][0]), "+v"(wbx[2][1]), "+v"(wbx[3][0]), "+v"(wbx[3][1]));
    asm volatile("" : "+v"(wbh[0][0]), "+v"(wbh[0][1]), "+v"(wbh[1][0]), "+v"(wbh[1][1]),
                      "+v"(wbh[2][0]), "+v"(wbh[2][1]), "+v"(wbh[3][0]), "+v"(wbh[3][1]),
                      "+v"(wbh[4][0]), "+v"(wbh[4][1]), "+v"(wbh[5][0]), "+v"(wbh[5][1]),
                      "+v"(wbh[6][0]), "+v"(wbh[6][1]), "+v"(wbh[7][0]), "+v"(wbh[7][1]));

    f32x4 acc0 = {0.f,0.f,0.f,0.f}, acc1 = {0.f,0.f,0.f,0.f};

    // phase X: obs_t @ Wx — retires while we wait on flags
    #pragma unroll
    for (int ks = 0; ks < 4; ++ks) {
      acc0 = __builtin_amdgcn_mfma_f32_16x16x32_bf16(ax[ks], wbx[ks][0], acc0, 0, 0, 0);
      acc1 = __builtin_amdgcn_mfma_f32_16x16x32_bf16(ax[ks], wbx[ks][1], acc1, 0, 0, 0);
    }

    // poll: one flag per lane, all >= want (monotone); ~1KB/WG per round
    {
      const u32 want = TAGB + (u32)t;
      int spin = 1 << 16;                    // bailout: fail visibly, never hang
      for (;;) {
        const u32 f = __hip_atomic_load(pollp, __ATOMIC_RELAXED, __HIP_MEMORY_SCOPE_AGENT);
        if (__all((int)(f - want) >= 0)) break;
        if (--spin == 0) break;
      }
    }

    // obs prefetch for t+1 (plain loads, fly with the h loads)
    bf16x8 axn[4];
    {
      const int tn = (t+1 < T_) ? t+1 : t;
      const u16* Axn = obsT + ((long)tn*B_ + arow)*NOBS + kh*128 + lq*8;
      #pragma unroll
      for (int ks = 0; ks < 4; ++ks) axn[ks] = *(const bf16x8*)(Axn + ks*32);
    }

    // h fragment loads: 8 x 16B, coherent, ONE round trip
    union { u32x4 u; bf16x8 v; } hf[8];
    {
      const u16* addr = hp + ((long)(t & 3) << 16) + fofs;
      #pragma unroll
      for (int ks = 0; ks < 8; ++ks)
        asm volatile("global_load_dwordx4 %0, %1, off offset:%2 sc0 sc1"
                     : "=v"(hf[ks].u) : "v"(addr), "i"(ks*64));
      asm volatile("s_waitcnt vmcnt(0)" ::: "memory");
      __builtin_amdgcn_sched_barrier(0);
    }

    // phase H: h @ Wh
    #pragma unroll
    for (int ks = 0; ks < 8; ++ks) {
      acc0 = __builtin_amdgcn_mfma_f32_16x16x32_bf16(hf[ks].v, wbh[ks][0], acc0, 0, 0, 0);
      acc1 = __builtin_amdgcn_mfma_f32_16x16x32_bf16(hf[ks].v, wbh[ks][1], acc1, 0, 0, 0);
    }
    #pragma unroll
    for (int ks = 0; ks < 4; ++ks) ax[ks] = axn[ks];

    // split-K partials to LDS  (D layout: col=lane&15, row=(lane>>4)*4+q)
    {
      const int zr0 = lq*4, zc = C0 + l15;
      #pragma unroll
      for (int q = 0; q < 4; ++q) {
        zs[kh][(zr0+q)*ZW + zc]      = acc0[q];
        zs[kh][(zr0+q)*ZW + zc + 16] = acc1[q];
      }
    }
    __syncthreads();

    // epilogue: 128 threads, 2 units each; store data granule immediately
    unsigned h01 = 0; int bq = 0;
    if (tid < 128) {
      const int rr = tid >> 3, pp = tid & 7;
      float hv2[2], cn2[2];
      #pragma unroll
      for (int u = 0; u < 2; ++u) {
        const int sl = 2*pp + u;
        const float* z0 = &zs[0][rr*ZW];
        const float* z1 = &zs[1][rr*ZW];
        const float zi = z0[sl]    + z1[sl]    + bsl[sl];
        const float zf = z0[16+sl] + z1[16+sl] + bsl[16+sl];
        const float zg = z0[32+sl] + z1[32+sl] + bsl[32+sl];
        const float zo = z0[48+sl] + z1[48+sl] + bsl[48+sl];
        const float cv = cst[rr*16 + sl];
        const float cn = sigm(zf)*cv + sigm(zi)*tanh_f(zg);
        hv2[u] = sigm(zo)*tanh_f(cn);
        cn2[u] = cn;
        cst[rr*16 + sl] = cn;
      }
      h01 = (unsigned)f2b(hv2[0]) | ((unsigned)f2b(hv2[1]) << 16);
      bq = rb0 + rr;
      if (t < T_-1) {
        u16* wp = hp + ((long)((t+1) & 3) << 16) + ((long)bq*H_ + S0 + 2*pp);
        __hip_atomic_store((u32*)wp, h01, __ATOMIC_RELAXED, __HIP_MEMORY_SCOPE_AGENT);
      }
      if (t == T_-1) {
        outh[bq*H_ + S0 + 2*pp]     = hv2[0];
        outh[bq*H_ + S0 + 2*pp + 1] = hv2[1];
        outc[bq*H_ + S0 + 2*pp]     = cn2[0];
        outc[bq*H_ + S0 + 2*pp + 1] = cn2[1];
      }
    }
    // release: drain data stores, then barrier, then flag
    asm volatile("s_waitcnt vmcnt(0)" ::: "memory");
    __syncthreads();
    if (tid == 0 && t < T_-1)
      __hip_atomic_store(myflag, TAGB + (u32)(t+1), __ATOMIC_RELAXED, __HIP_MEMORY_SCOPE_AGENT);
    // ys store off the critical path (after the flag)
    if (tid < 128) {
      const int pp = tid & 7;
      *(u32*)(ys + ((long)bq*T_ + t)*H_ + S0 + 2*pp) = h01;
    }
  }
}

// ---------------- head ----------------
__global__ __launch_bounds__(256) void k_head(const u16* __restrict__ X, const u16* __restrict__ WoT,
    const float* __restrict__ bo, const float* __restrict__ amin, const float* __restrict__ amax,
    float* __restrict__ out)
{
  __shared__ u16 Ws[NACT*H_];
  __shared__ float sc[3*NACT];
  const int tid = threadIdx.x;
  #pragma unroll
  for (int q = 0; q < 8; ++q)
    ((float4*)Ws)[q*256 + tid] = ((const float4*)WoT)[q*256 + tid];
  if (tid < NACT) { sc[tid] = bo[tid]; sc[NACT+tid] = amin[tid]; sc[2*NACT+tid] = amax[tid]; }
  __syncthreads();
  const long r = (long)blockIdx.x*64 + (tid >> 2);
  const int c0 = (tid & 3)*8;
  float acc[8];
  #pragma unroll
  for (int c = 0; c < 8; ++c) acc[c] = 0.f;
  const u16* Arow = X + r*H_;
  for (int kc = 0; kc < H_/8; ++kc) {
    bf16x8 a = *(const bf16x8*)(Arow + kc*8);
    float av[8];
    #pragma unroll
    for (int j = 0; j < 8; ++j) av[j] = b2f((u16)a[j]);
    #pragma unroll
    for (int c = 0; c < 8; ++c) {
      bf16x8 w = *(const bf16x8*)(Ws + (c0+c)*H_ + kc*8);
      #pragma unroll
      for (int j = 0; j < 8; ++j) acc[c] += av[j] * b2f((u16)w[j]);
    }
  }
  #pragma unroll
  for (int c = 0; c < 8; ++c) {
    const int cc = c0 + c;
    const float y = acc[c] + sc[cc];
    const float tv = tanhf(y);
    out[r*NACT + cc] = 0.5f*(tv*(sc[2*NACT+cc]-sc[NACT+cc]) + (sc[2*NACT+cc]+sc[NACT+cc]));
  }
}

extern "C" void kernel_launch(void* const* d_in, const int* in_sizes, int n_in,
                              void* d_out, int out_size, void* d_ws, size_t ws_size,
                              hipStream_t stream) {
  const float* obs = (const float*)d_in[0];
  const float* h0  = (const float*)d_in[1];
  const float* c0  = (const float*)d_in[2];
  const float* Wx  = (const float*)d_in[3];
  const float* Wh  = (const float*)d_in[4];
  const float* bb  = (const float*)d_in[5];
  const float* W1  = (const float*)d_in[6];
  const float* b1  = (const float*)d_in[7];
  const float* W2  = (const float*)d_in[8];
  const float* b2  = (const float*)d_in[9];
  const float* Wo  = (const float*)d_in[10];
  const float* bo  = (const float*)d_in[11];
  const float* amin= (const float*)d_in[12];
  const float* amax= (const float*)d_in[13];

  char* ws = (char*)d_ws;
  // workspace layout (bytes), end ~172.5 MiB (same proven footprint):
  u16* obsT  = (u16*)(ws + 0);                 // (T,B,NOBS) bf16, 32 MiB
  u16* ys    = (u16*)(ws + 33554432);          // (B,T,H) bf16, 64 MiB
  u16* t1    = (u16*)(ws + 100663296);         // 64 MiB (dead during scan)
  u16* t2    = (u16*)(ws + 33554432);          // alias ys (dead after W1-GEMM)
  u16* WxT   = (u16*)(ws + 167772160);         // (G4, NOBS)  1 MiB
  u16* WhT   = (u16*)(ws + 168820736);         // (G4, H)     2 MiB
  u16* W1T   = (u16*)(ws + 170917888);         // 0.5 MiB
  u16* W2T   = (u16*)(ws + 171442176);         // 0.5 MiB
  u16* WoT   = (u16*)(ws + 171966464);         // 64 KiB
  u16* hp    = (u16*)(ws + 171999232);         // 4 h planes x 128 KiB = 512 KiB
  u32* flags = (u32*)(ws + 172523520);         // 256 x 4B

  float* outA = (float*)d_out;
  float* outh = outA + (long)M_*NACT;
  float* outc = outh + B_*H_;

  k_cvt_obsT<<<M_*NOBS/8/256, 256, 0, stream>>>(obs, obsT);
  k_inith<<<B_, 256, 0, stream>>>(h0, hp, flags);     // plane 0 = h0; flags = TAGB
  k_transpose<<<2048, 256, 0, stream>>>(Wx, WxT, NOBS, G4);
  k_transpose<<<4096, 256, 0, stream>>>(Wh, WhT, H_, G4);
  k_transpose<<<1024, 256, 0, stream>>>(W1, W1T, H_, H_);
  k_transpose<<<1024, 256, 0, stream>>>(W2, W2T, H_, H_);
  k_transpose<<<64,   256, 0, stream>>>(Wo, WoT, H_, NACT);

  // persistent scan: 256 co-resident WGs (1/CU), flag-released h exchange
  k_scan<<<256, 256, 0, stream>>>(obsT, WxT, WhT, bb, c0, hp, flags, ys, outh, outc);

  // MLP head
  k_gemm_bt<1><<<(M_/128)*(H_/128), 256, 0, stream>>>(ys, W1T, t1, b1, M_, H_, H_);
  k_gemm_bt<1><<<(M_/128)*(H_/128), 256, 0, stream>>>(t1, W2T, t2, b2, M_, H_, H_);
  k_head<<<M_/64, 256, 0, stream>>>(t2, WoT, bo, amin, amax, outA);
}